// Round 1
// baseline (129.425 us; speedup 1.0000x reference)
//
#include <hip/hip_runtime.h>

// RBF trainable activation (optox RbfAct, group=1):
//   y[n,c,h,w] = sum_{j=0..30} w[c,j] * exp(-112.5 * (x - mu_j)^2),
//   mu_j = -1 + j/15,  sigma = 1/15,  inv_2s2 = 112.5.
//
// Strategy: map x into center-index space u = (x+1)*15 (centers at integers
// 0..30). Term at distance k from nearest center scales as exp(-0.5*k^2):
// |k|>=5 contributes < 3.7e-6, so truncate to the 9 nearest centers (R=4).
// Truncation error <= ~8e-6 << 4.4e-2 threshold. Per-lane center index is
// data-dependent -> gather weights from a per-channel LDS table zero-padded
// by R on each side (out-of-range centers read weight 0, branch-free).
// Direct per-term eval underflows to 0 for |x|>>1 (no inf*0 NaN hazard).

constexpr int KW  = 31;            // centers / weights per channel
constexpr int R   = 4;             // truncation radius (center units)
constexpr int TAB = KW + 2 * R;    // padded LDS table: 39

// exp(-0.5*(u-j)^2) = exp2(-(S*(u-j))^2),  S = sqrt(0.5*log2(e))
#define S_CONST 0.84932840178f

__global__ __launch_bounds__(256) void rbf_act_kernel(
    const float* __restrict__ x,
    const float* __restrict__ w,
    float* __restrict__ y)
{
    __shared__ float lw[TAB];
    const int bid = blockIdx.x;
    const int tid = threadIdx.x;
    // 4 blocks of 4096 elems per (n,c) plane of 128*128 = 16384; c uniform.
    const int c = (bid >> 2) & 63;
    if (tid < TAB) {
        const int j = tid - R;
        lw[tid] = (j >= 0 && j < KW) ? w[c * KW + j] : 0.0f;
    }
    __syncthreads();

    const size_t base = (size_t)bid * 4096;
    const float4* __restrict__ xv = (const float4*)(x + base);
    float4*       __restrict__ yv = (float4*)(y + base);

    #pragma unroll
    for (int i = 0; i < 4; ++i) {
        float4 v = xv[tid + i * 256];
        float4 o;
        float* vp = (float*)&v;
        float* op = (float*)&o;
        #pragma unroll
        for (int e = 0; e < 4; ++e) {
            const float u   = vp[e] * 15.0f + 15.0f;      // center-index space
            float j0f = __builtin_rintf(u);               // v_rndne_f32
            j0f = fminf(fmaxf(j0f, 0.0f), 30.0f);         // clamp to grid
            const int   j0  = (int)j0f;
            const float duS = (u - j0f) * S_CONST;        // |du|<=0.5 (interior)
            float acc = 0.0f;
            #pragma unroll
            for (int k = -R; k <= R; ++k) {
                const float t   = duS - (float)k * S_CONST;  // const folds
                const float arg = (-t) * t;                  // neg src modifier
                const float p   = exp2f(arg);                // v_exp_f32
                acc = fmaf(lw[j0 + k + R], p, acc);          // ds_read + v_fma
            }
            op[e] = acc;
        }
        yv[tid + i * 256] = o;
    }
}

extern "C" void kernel_launch(void* const* d_in, const int* in_sizes, int n_in,
                              void* d_out, int out_size, void* d_ws, size_t ws_size,
                              hipStream_t stream) {
    const float* x = (const float*)d_in[0];
    const float* w = (const float*)d_in[1];
    float*       y = (float*)d_out;
    const int total   = in_sizes[0];       // 16*64*128*128 = 16777216
    const int nblocks = total / 4096;      // 4096 blocks, 16 elems/thread
    rbf_act_kernel<<<nblocks, 256, 0, stream>>>(x, w, y);
}

// Round 2
// 111.843 us; speedup vs baseline: 1.1572x; 1.1572x over previous
//
#include <hip/hip_runtime.h>

// RBF trainable activation: y = sum_{j=0..30} w[c,j]*exp(-112.5*(x-mu_j)^2),
// mu_j = -1 + j/15. In center-index space u = 15x+15, sigma = 1 index unit.
//
// R2 scheme: 7-tap window at m = j0-3 (j0 = clamped nearest center).
// Factorize exp(-0.5*(du'-k)^2) = g * r^k * c_k with du' = u-m,
//   g = exp(-0.5*du'^2), r = exp(du'), c_k = exp(-0.5*k^2) (constants).
// => 2 transcendentals/elem instead of 9, via raw v_exp_f32
// (__builtin_amdgcn_exp2f — avoids the OCML exp2 wrapper that made R1
// VALU-bound). du clamped to +-7.5: exp2 args in [-80,+16], r^6 <= 2.3e27,
// no overflow/denormal path, and truncation error for clamped lanes <= 4e-5.
// Window truncation (R=3): <= 2*exp(-6.125)*|w| ~ 4.5e-3 << 4.4e-2 threshold.
//
// Weights gathered from per-channel LDS table, zero-padded by R each side
// (edge windows read 0 branch-free). 37 entries -> <=2 rows/bank -> free.

constexpr int KW  = 31;
constexpr int R   = 3;
constexpr int TAB = KW + 2 * R;   // 37

#define LOG2E   1.44269504089f    // log2(e)
#define SQ_C    0.84932180028f    // sqrt(0.5*log2(e)); exp(-0.5 t^2)=exp2(-(SQ*t)^2)

#if defined(__has_builtin) && __has_builtin(__builtin_amdgcn_exp2f)
#define FAST_EXP2(a) __builtin_amdgcn_exp2f(a)
#else
#define FAST_EXP2(a) exp2f(a)
#endif

__global__ __launch_bounds__(256) void rbf_act_kernel(
    const float* __restrict__ x,
    const float* __restrict__ w,
    float* __restrict__ y)
{
    __shared__ float lw[TAB];
    const int bid = blockIdx.x;
    const int tid = threadIdx.x;
    // 4 blocks of 4096 elems per (n,c) plane of 128*128 = 16384; c uniform.
    const int c = (bid >> 2) & 63;
    if (tid < TAB) {
        const int j = tid - R;
        lw[tid] = (j >= 0 && j < KW) ? w[c * KW + j] : 0.0f;
    }
    __syncthreads();

    // c_k = exp(-0.5*k^2), k = 0..6
    const float C0 = 1.0f;
    const float C1 = 0.60653065971f;
    const float C2 = 0.13533528324f;
    const float C3 = 0.01110899654f;
    const float C4 = 3.35462628e-4f;
    const float C5 = 3.72665317e-6f;
    const float C6 = 1.52299797e-8f;

    const size_t base = (size_t)bid * 4096;
    const float4* __restrict__ xv = (const float4*)(x + base);
    float4*       __restrict__ yv = (float4*)(y + base);

    #pragma unroll
    for (int i = 0; i < 4; ++i) {
        float4 v = xv[tid + i * 256];
        float4 o;
        float* vp = (float*)&v;
        float* op = (float*)&o;
        #pragma unroll
        for (int e = 0; e < 4; ++e) {
            const float u   = __builtin_fmaf(vp[e], 15.0f, 15.0f);
            float j0f = __builtin_rintf(u);               // v_rndne_f32
            j0f = fminf(fmaxf(j0f, 0.0f), 30.0f);         // v_med3_f32
            const int j0 = (int)j0f;
            float du = u - j0f;
            du = fminf(fmaxf(du, -7.5f), 7.5f);           // range safety
            const float dup = du + 3.0f;                  // in [-4.5, 10.5]
            const float r  = FAST_EXP2(LOG2E * dup);      // exp(du')
            const float t  = SQ_C * dup;
            const float g  = FAST_EXP2(-t * t);           // exp(-0.5 du'^2)
            const float r2 = r * r;
            const float r3 = r2 * r;
            const float r4 = r2 * r2;
            const float r5 = r3 * r2;
            const float r6 = r3 * r3;
            // window j = j0-3+k -> LDS index j0+k (pad R=3)
            const float* wp = lw + j0;
            float acc;
            acc = wp[0] * C0;
            acc = __builtin_fmaf(wp[1] * C1, r,  acc);
            acc = __builtin_fmaf(wp[2] * C2, r2, acc);
            acc = __builtin_fmaf(wp[3] * C3, r3, acc);
            acc = __builtin_fmaf(wp[4] * C4, r4, acc);
            acc = __builtin_fmaf(wp[5] * C5, r5, acc);
            acc = __builtin_fmaf(wp[6] * C6, r6, acc);
            op[e] = g * acc;
        }
        yv[tid + i * 256] = o;
    }
}

extern "C" void kernel_launch(void* const* d_in, const int* in_sizes, int n_in,
                              void* d_out, int out_size, void* d_ws, size_t ws_size,
                              hipStream_t stream) {
    const float* x = (const float*)d_in[0];
    const float* w = (const float*)d_in[1];
    float*       y = (float*)d_out;
    const int total   = in_sizes[0];       // 16*64*128*128 = 16777216
    const int nblocks = total / 4096;      // 4096 blocks, 16 elems/thread
    rbf_act_kernel<<<nblocks, 256, 0, stream>>>(x, w, y);
}

// Round 3
// 110.894 us; speedup vs baseline: 1.1671x; 1.0086x over previous
//
#include <hip/hip_runtime.h>

// RBF trainable activation: y = sum_{j=0..30} w[c,j]*exp(-112.5*(x-mu_j)^2),
// mu_j = -1 + j/15. Center-index space u = 15x+15, sigma = 1 index unit.
//
// R3 scheme: per-block LDS lookup table. c is block-uniform, and y(u) is a
// smooth fixed 1-D function per channel, so each block builds a 1024-entry
// table of y over u in [-5,35] (h = 40/1023 ~ 0.039; linear-interp error
// h^2/8*|y''| ~ 6e-4) using the R2 factorized 7-tap window eval
// (2 exps/entry, 4 entries/thread -> negligible vs 4096 elems/block).
// Main loop per element: 1 fma (index map), clamp, floor, frac,
// one ds_read2_b32 (tbl[i], tbl[i+1]), lerp. Replaces R2's 7 data-dependent
// LDS gathers + 2 exps + 13-op fma chain per element -> memory-bound.
// Outside [-5,35] the true y <= exp(-8)*sum|w| ~ 1e-3: table edges ~0,
// clamped lanes are fine. Total error ~6e-3 << 4.4e-2 threshold.

constexpr int KW   = 31;
constexpr int R    = 3;
constexpr int TAB  = KW + 2 * R;   // 37 padded weights
constexpr int TN   = 1024;         // table entries
#define U0      -5.0f
#define U1      35.0f
#define HU      ((U1 - U0) / (TN - 1))          // 40/1023
#define INV_HU  ((TN - 1) / (U1 - U0))          // 25.575
// t = (u - U0)*INV_HU, u = 15x+15  =>  t = x*(15*INV_HU) + 20*INV_HU
#define TSCALE  (15.0f * INV_HU)                // 383.625
#define TBIAS   (20.0f * INV_HU)                // 511.5

#define LOG2E   1.44269504089f
#define SQ_C    0.84932180028f    // sqrt(0.5*log2(e))

#if defined(__has_builtin) && __has_builtin(__builtin_amdgcn_exp2f)
#define FAST_EXP2(a) __builtin_amdgcn_exp2f(a)
#else
#define FAST_EXP2(a) exp2f(a)
#endif

__global__ __launch_bounds__(256) void rbf_act_kernel(
    const float* __restrict__ x,
    const float* __restrict__ w,
    float* __restrict__ y)
{
    __shared__ float lw[TAB];
    __shared__ float tbl[TN];
    const int bid = blockIdx.x;
    const int tid = threadIdx.x;
    // 4 blocks of 4096 elems per (n,c) plane of 128*128 = 16384; c uniform.
    const int c = (bid >> 2) & 63;
    if (tid < TAB) {
        const int j = tid - R;
        lw[tid] = (j >= 0 && j < KW) ? w[c * KW + j] : 0.0f;
    }
    __syncthreads();

    // c_k = exp(-0.5*k^2), k = 0..6 (window position k-3)
    const float C0 = 1.0f;
    const float C1 = 0.60653065971f;
    const float C2 = 0.13533528324f;
    const float C3 = 0.01110899654f;
    const float C4 = 3.35462628e-4f;
    const float C5 = 3.72665317e-6f;
    const float C6 = 1.52299797e-8f;

    // Build table: 4 entries per thread.
    #pragma unroll
    for (int kk = 0; kk < TN / 256; ++kk) {
        const int idx = tid + kk * 256;
        const float u = U0 + (float)idx * HU;
        float j0f = __builtin_rintf(u);
        j0f = fminf(fmaxf(j0f, 0.0f), 30.0f);
        const int j0 = (int)j0f;
        const float dup = (u - j0f) + 3.0f;         // in [-2, 8]
        const float r  = FAST_EXP2(LOG2E * dup);    // exp(du')
        const float t  = SQ_C * dup;
        const float g  = FAST_EXP2(-t * t);         // exp(-0.5 du'^2)
        const float r2 = r * r;
        const float r3 = r2 * r;
        const float r4 = r2 * r2;
        const float r5 = r3 * r2;
        const float r6 = r3 * r3;
        const float* wp = lw + j0;                  // window j0-3+k -> lw[j0+k]
        float acc;
        acc = wp[0] * C0;
        acc = __builtin_fmaf(wp[1] * C1, r,  acc);
        acc = __builtin_fmaf(wp[2] * C2, r2, acc);
        acc = __builtin_fmaf(wp[3] * C3, r3, acc);
        acc = __builtin_fmaf(wp[4] * C4, r4, acc);
        acc = __builtin_fmaf(wp[5] * C5, r5, acc);
        acc = __builtin_fmaf(wp[6] * C6, r6, acc);
        tbl[idx] = g * acc;
    }
    __syncthreads();

    const size_t base = (size_t)bid * 4096;
    const float4* __restrict__ xv = (const float4*)(x + base);
    float4*       __restrict__ yv = (float4*)(y + base);

    #pragma unroll
    for (int i = 0; i < 4; ++i) {
        float4 v = xv[tid + i * 256];
        float4 o;
        float* vp = (float*)&v;
        float* op = (float*)&o;
        #pragma unroll
        for (int e = 0; e < 4; ++e) {
            float t = __builtin_fmaf(vp[e], TSCALE, TBIAS);
            t = fminf(fmaxf(t, 0.0f), (float)(TN - 1) - 0.001f);  // v_med3
            const float fi = __builtin_truncf(t);
            const float f  = t - fi;
            const int   i0 = (int)fi;
            const float y0 = tbl[i0];
            const float y1 = tbl[i0 + 1];           // ds_read2_b32 pair
            op[e] = __builtin_fmaf(f, y1 - y0, y0);
        }
        yv[tid + i * 256] = o;
    }
}

extern "C" void kernel_launch(void* const* d_in, const int* in_sizes, int n_in,
                              void* d_out, int out_size, void* d_ws, size_t ws_size,
                              hipStream_t stream) {
    const float* x = (const float*)d_in[0];
    const float* w = (const float*)d_in[1];
    float*       y = (float*)d_out;
    const int total   = in_sizes[0];       // 16*64*128*128 = 16777216
    const int nblocks = total / 4096;      // 4096 blocks, 16 elems/thread
    rbf_act_kernel<<<nblocks, 256, 0, stream>>>(x, w, y);
}

// Round 5
// 109.731 us; speedup vs baseline: 1.1795x; 1.0106x over previous
//
#include <hip/hip_runtime.h>

// RBF trainable activation: y = sum_{j=0..30} w[c,j]*exp(-112.5*(x-mu_j)^2),
// mu_j = -1 + j/15. Center-index space u = 15x+15, sigma = 1 index unit.
//
// R5 = R4 with the nontemporal-store type fixed (native clang vector, not
// HIP_vector_type). Design:
//  - 32 elems/thread: 8 float4 loads issued back-to-back up front
//    (8 in flight/wave; latency overlaps table build + barrier drain).
//  - Single __syncthreads(): LUT build reads w straight from global
//    (124 B/channel, L1-cached; branch-free clamp + select for edge taps).
//  - 2048 blocks (8192 elems each) halve per-block prologue count.
//  - Nontemporal y stores: pure streaming writes, don't thrash L3.
// Numerics: 1024-entry LUT over u in [-5,35] built with the factorized
// 7-tap window (2 exps/entry); lerp error ~6e-4, window truncation ~4.5e-3,
// edge clamp <=1e-3 -> total << 4.4e-2 threshold.

constexpr int KW = 31;
constexpr int TN = 1024;
#define U0      -5.0f
#define U1      35.0f
#define HU      ((U1 - U0) / (TN - 1))
#define INV_HU  ((TN - 1) / (U1 - U0))
#define TSCALE  (15.0f * INV_HU)     // t = x*TSCALE + TBIAS
#define TBIAS   (20.0f * INV_HU)

#define LOG2E   1.44269504089f
#define SQ_C    0.84932180028f       // sqrt(0.5*log2(e))

#if defined(__has_builtin) && __has_builtin(__builtin_amdgcn_exp2f)
#define FAST_EXP2(a) __builtin_amdgcn_exp2f(a)
#else
#define FAST_EXP2(a) exp2f(a)
#endif

typedef float vfloat4 __attribute__((ext_vector_type(4)));

__global__ __launch_bounds__(256) void rbf_act_kernel(
    const float* __restrict__ x,
    const float* __restrict__ w,
    float* __restrict__ y)
{
    __shared__ float tbl[TN];
    const int bid = blockIdx.x;
    const int tid = threadIdx.x;
    // 8192 elems/block; plane (n,c) = 16384 elems = 2 blocks; c = (bid>>1)%64
    const int c = (bid >> 1) & 63;

    const size_t base = (size_t)bid * 8192;
    const vfloat4* __restrict__ xv = (const vfloat4*)(x + base);
    vfloat4*       __restrict__ yv = (vfloat4*)(y + base);

    // Phase 0: issue all 8 streaming loads (stay in flight through build).
    vfloat4 v[8];
    #pragma unroll
    for (int i = 0; i < 8; ++i) v[i] = xv[tid + i * 256];

    // Phase 1: build LUT, 4 entries/thread, w read direct from global (L1).
    const float C0 = 1.0f;
    const float C1 = 0.60653065971f;
    const float C2 = 0.13533528324f;
    const float C3 = 0.01110899654f;
    const float C4 = 3.35462628e-4f;
    const float C5 = 3.72665317e-6f;
    const float C6 = 1.52299797e-8f;
    const float* __restrict__ wr = w + c * KW;
    #pragma unroll
    for (int kk = 0; kk < TN / 256; ++kk) {
        const int idx = tid + kk * 256;
        const float u = U0 + (float)idx * HU;
        float j0f = __builtin_rintf(u);
        j0f = fminf(fmaxf(j0f, 0.0f), 30.0f);
        const int j0 = (int)j0f;
        const float dup = (u - j0f) + 3.0f;          // in [-2, 8]
        const float r  = FAST_EXP2(LOG2E * dup);     // exp(du')
        const float t  = SQ_C * dup;
        const float g  = FAST_EXP2(-t * t);          // exp(-0.5 du'^2)
        const float r2 = r * r;
        const float r3 = r2 * r;
        const float r4 = r2 * r2;
        const float r5 = r3 * r2;
        const float r6 = r3 * r3;
        // taps j = j0-3+k; branch-free: clamp index, zero if clamped
        float wv[7];
        #pragma unroll
        for (int k = 0; k < 7; ++k) {
            const int jj = j0 - 3 + k;
            const int jc = min(max(jj, 0), KW - 1);
            const float wj = wr[jc];
            wv[k] = (jj == jc) ? wj : 0.0f;
        }
        float acc;
        acc = wv[0] * C0;
        acc = __builtin_fmaf(wv[1] * C1, r,  acc);
        acc = __builtin_fmaf(wv[2] * C2, r2, acc);
        acc = __builtin_fmaf(wv[3] * C3, r3, acc);
        acc = __builtin_fmaf(wv[4] * C4, r4, acc);
        acc = __builtin_fmaf(wv[5] * C5, r5, acc);
        acc = __builtin_fmaf(wv[6] * C6, r6, acc);
        tbl[idx] = g * acc;
    }
    __syncthreads();

    // Phase 2: LUT lerp + nontemporal streaming stores.
    #pragma unroll
    for (int i = 0; i < 8; ++i) {
        vfloat4 vv = v[i];
        vfloat4 o;
        #pragma unroll
        for (int e = 0; e < 4; ++e) {
            float t = __builtin_fmaf(vv[e], TSCALE, TBIAS);
            t = fminf(fmaxf(t, 0.0f), (float)(TN - 1) - 0.001f);  // v_med3
            const float fi = __builtin_truncf(t);
            const float f  = t - fi;
            const int   i0 = (int)fi;
            const float y0 = tbl[i0];
            const float y1 = tbl[i0 + 1];            // ds_read2_b32 pair
            o[e] = __builtin_fmaf(f, y1 - y0, y0);
        }
        __builtin_nontemporal_store(o, &yv[tid + i * 256]);
    }
}

extern "C" void kernel_launch(void* const* d_in, const int* in_sizes, int n_in,
                              void* d_out, int out_size, void* d_ws, size_t ws_size,
                              hipStream_t stream) {
    const float* x = (const float*)d_in[0];
    const float* w = (const float*)d_in[1];
    float*       y = (float*)d_out;
    const int total   = in_sizes[0];       // 16*64*128*128 = 16777216
    const int nblocks = total / 8192;      // 2048 blocks, 32 elems/thread
    rbf_act_kernel<<<nblocks, 256, 0, stream>>>(x, w, y);
}

// Round 6
// 109.088 us; speedup vs baseline: 1.1864x; 1.0059x over previous
//
#include <hip/hip_runtime.h>

// RBF trainable activation: y = sum_{j=0..30} w[c,j]*exp(-112.5*(x-mu_j)^2),
// mu_j = -1 + j/15. Center-index space u = 15x+15, sigma = 1 index unit.
//
// R6: software-pipelined stream (prefetch distance 4) over R5's LUT scheme.
// R3 failed latency-bound (1 load in flight); R5 failed phase-serialized
// (all loads drained at the barrier, then pure write phase — read and write
// HBM streams never overlap). R6: prefetch chunks 0-3 before the LUT build
// (latency hidden under build + barrier drain); after the barrier, iteration
// i computes chunk i, ISSUES the load for chunk i+4, then stores chunk i —
// keeping ~4 loads + stores concurrently in flight per wave, a continuous
// bidirectional HBM stream like a D2D copy (6.3 TB/s regime).
// Numerics identical to R3/R5: 1024-entry LUT over u in [-5,35], factorized
// 7-tap window build (2 exps/entry); total error ~6e-3 << 4.4e-2 threshold.

constexpr int KW = 31;
constexpr int TN = 1024;
#define U0      -5.0f
#define U1      35.0f
#define HU      ((U1 - U0) / (TN - 1))
#define INV_HU  ((TN - 1) / (U1 - U0))
#define TSCALE  (15.0f * INV_HU)     // t = x*TSCALE + TBIAS
#define TBIAS   (20.0f * INV_HU)

#define LOG2E   1.44269504089f
#define SQ_C    0.84932180028f       // sqrt(0.5*log2(e))

#if defined(__has_builtin) && __has_builtin(__builtin_amdgcn_exp2f)
#define FAST_EXP2(a) __builtin_amdgcn_exp2f(a)
#else
#define FAST_EXP2(a) exp2f(a)
#endif

typedef float vfloat4 __attribute__((ext_vector_type(4)));

__global__ __launch_bounds__(256) void rbf_act_kernel(
    const float* __restrict__ x,
    const float* __restrict__ w,
    float* __restrict__ y)
{
    __shared__ float tbl[TN];
    const int bid = blockIdx.x;
    const int tid = threadIdx.x;
    // 8192 elems/block; plane (n,c) = 16384 elems = 2 blocks; c = (bid>>1)%64
    const int c = (bid >> 1) & 63;

    const size_t base = (size_t)bid * 8192;
    const vfloat4* __restrict__ xv = (const vfloat4*)(x + base);
    vfloat4*       __restrict__ yv = (vfloat4*)(y + base);

    // Prefetch chunks 0-3 (latency overlaps LUT build + barrier drain).
    vfloat4 buf[4];
    #pragma unroll
    for (int i = 0; i < 4; ++i) buf[i] = xv[tid + i * 256];

    // LUT build: 4 entries/thread, w read direct from global (L1).
    const float C0 = 1.0f;
    const float C1 = 0.60653065971f;
    const float C2 = 0.13533528324f;
    const float C3 = 0.01110899654f;
    const float C4 = 3.35462628e-4f;
    const float C5 = 3.72665317e-6f;
    const float C6 = 1.52299797e-8f;
    const float* __restrict__ wr = w + c * KW;
    #pragma unroll
    for (int kk = 0; kk < TN / 256; ++kk) {
        const int idx = tid + kk * 256;
        const float u = U0 + (float)idx * HU;
        float j0f = __builtin_rintf(u);
        j0f = fminf(fmaxf(j0f, 0.0f), 30.0f);
        const int j0 = (int)j0f;
        const float dup = (u - j0f) + 3.0f;          // in [-2, 8]
        const float r  = FAST_EXP2(LOG2E * dup);     // exp(du')
        const float t  = SQ_C * dup;
        const float g  = FAST_EXP2(-t * t);          // exp(-0.5 du'^2)
        const float r2 = r * r;
        const float r3 = r2 * r;
        const float r4 = r2 * r2;
        const float r5 = r3 * r2;
        const float r6 = r3 * r3;
        // taps j = j0-3+k; branch-free: clamp index, zero if clamped
        float wv[7];
        #pragma unroll
        for (int k = 0; k < 7; ++k) {
            const int jj = j0 - 3 + k;
            const int jc = min(max(jj, 0), KW - 1);
            const float wj = wr[jc];
            wv[k] = (jj == jc) ? wj : 0.0f;
        }
        float acc;
        acc = wv[0] * C0;
        acc = __builtin_fmaf(wv[1] * C1, r,  acc);
        acc = __builtin_fmaf(wv[2] * C2, r2, acc);
        acc = __builtin_fmaf(wv[3] * C3, r3, acc);
        acc = __builtin_fmaf(wv[4] * C4, r4, acc);
        acc = __builtin_fmaf(wv[5] * C5, r5, acc);
        acc = __builtin_fmaf(wv[6] * C6, r6, acc);
        tbl[idx] = g * acc;
    }
    __syncthreads();

    // Pipelined stream: compute chunk i, issue load i+4, store chunk i.
    #pragma unroll
    for (int i = 0; i < 8; ++i) {
        vfloat4 vv = buf[i & 3];
        if (i + 4 < 8) buf[i & 3] = xv[tid + (i + 4) * 256];  // prefetch
        vfloat4 o;
        #pragma unroll
        for (int e = 0; e < 4; ++e) {
            float t = __builtin_fmaf(vv[e], TSCALE, TBIAS);
            t = fminf(fmaxf(t, 0.0f), (float)(TN - 1) - 0.001f);  // v_med3
            const float fi = __builtin_truncf(t);
            const float f  = t - fi;
            const int   i0 = (int)fi;
            const float y0 = tbl[i0];
            const float y1 = tbl[i0 + 1];            // ds_read2_b32 pair
            o[e] = __builtin_fmaf(f, y1 - y0, y0);
        }
        __builtin_nontemporal_store(o, &yv[tid + i * 256]);
    }
}

extern "C" void kernel_launch(void* const* d_in, const int* in_sizes, int n_in,
                              void* d_out, int out_size, void* d_ws, size_t ws_size,
                              hipStream_t stream) {
    const float* x = (const float*)d_in[0];
    const float* w = (const float*)d_in[1];
    float*       y = (float*)d_out;
    const int total   = in_sizes[0];       // 16*64*128*128 = 16777216
    const int nblocks = total / 8192;      // 2048 blocks, 32 elems/thread
    rbf_act_kernel<<<nblocks, 256, 0, stream>>>(x, w, y);
}